// Round 13
// baseline (175.792 us; speedup 1.0000x reference)
//
#include <hip/hip_runtime.h>
#include <hip/hip_bf16.h>

#define D 128
#define SCAN_CHUNK 1024
#define TE 4096  // edges per partition block

typedef __attribute__((ext_vector_type(8))) short bf16x8;
typedef __attribute__((ext_vector_type(4))) float f32x4;
typedef __attribute__((ext_vector_type(2))) float f32x2;

// ---------- edge-index dtype detection (int64 vs int32, on-device) ----------
__device__ __forceinline__ bool ei_is64(const int* ei32) {
    return (ei32[1] | ei32[3] | ei32[5] | ei32[7]) == 0;
}
__device__ __forceinline__ int get_idx(const void* ei, bool is64, long long pos) {
    return is64 ? (int)((const long long*)ei)[pos] : ((const int*)ei)[pos];
}

// ---------- prep: x->fp8 | frag-major weight build | partition histogram ----------
__global__ __launch_bounds__(256) void prep_kernel(
    const float* __restrict__ x, unsigned* __restrict__ xq, long long ND, int ncvt,
    const float* __restrict__ Wl1, const float* __restrict__ Wr1,
    const float* __restrict__ Wl2, const float* __restrict__ Wr2,
    ushort* __restrict__ Wf1, ushort* __restrict__ Wf2,
    const void* __restrict__ ei, int E, int NB, int NBLK, int SH,
    int* __restrict__ histT) {
    __shared__ int h[512];
    const int t = threadIdx.x;
    int bid = blockIdx.x;

    if (bid < ncvt) {
        long long i = ((long long)bid * 256 + t) * 8;
        if (i + 7 < ND) {
            float4 v0 = *reinterpret_cast<const float4*>(x + i);
            float4 v1 = *reinterpret_cast<const float4*>(x + i + 4);
            int p0 = __builtin_amdgcn_cvt_pk_fp8_f32(v0.x, v0.y, 0, false);
            p0 = __builtin_amdgcn_cvt_pk_fp8_f32(v0.z, v0.w, p0, true);
            int p1 = __builtin_amdgcn_cvt_pk_fp8_f32(v1.x, v1.y, 0, false);
            p1 = __builtin_amdgcn_cvt_pk_fp8_f32(v1.z, v1.w, p1, true);
            *reinterpret_cast<uint2*>(reinterpret_cast<unsigned char*>(xq) + i) =
                make_uint2((unsigned)p0, (unsigned)p1);
        } else {
            for (; i < ND; ++i) {
                int pk = __builtin_amdgcn_cvt_pk_fp8_f32(x[i], x[i], 0, false);
                reinterpret_cast<unsigned char*>(xq)[i] = (unsigned char)(pk & 0xff);
            }
        }
        return;
    }
    bid -= ncvt;
    if (bid < 32) {
        int gid = bid * 256 + t;           // 8192 threads: 2 layers x 4096 slots
        int id = gid & 4095;
        const float* Wl = Wl1; const float* Wr = Wr1; ushort* Wf = Wf1;
        if (gid >= 4096) { Wl = Wl2; Wr = Wr2; Wf = Wf2; }
        int lane = id & 63, s = (id >> 6) & 7, j = id >> 9;
        int c = j * 16 + (lane & 15);
        int k = s * 32 + ((lane >> 4) << 3);  // 8 consecutive k from here
        const float* src = (k < 128) ? (Wl + c * 128 + k) : (Wr + c * 128 + (k - 128));
        float4 v0 = *reinterpret_cast<const float4*>(src);
        float4 v1 = *reinterpret_cast<const float4*>(src + 4);
        __hip_bfloat16 o[8];
        o[0] = __float2bfloat16(v0.x); o[1] = __float2bfloat16(v0.y);
        o[2] = __float2bfloat16(v0.z); o[3] = __float2bfloat16(v0.w);
        o[4] = __float2bfloat16(v1.x); o[5] = __float2bfloat16(v1.y);
        o[6] = __float2bfloat16(v1.z); o[7] = __float2bfloat16(v1.w);
        *reinterpret_cast<uint4*>(Wf + (size_t)id * 8) = *reinterpret_cast<uint4*>(o);
        return;
    }
    bid -= 32;
    // partition histogram over buckets for edge tile bid
    for (int b = t; b < 512; b += 256) h[b] = 0;
    bool is64 = ei_is64((const int*)ei);
    __syncthreads();
    const int base = bid * TE;
    for (int i = t; i < TE; i += 256) {
        int e = base + i;
        if (e < E) {
            int d = get_idx(ei, is64, (long long)E + e);
            atomicAdd(&h[d >> SH], 1);
        }
    }
    __syncthreads();
    for (int b = t; b < NB; b += 256) histT[b * NBLK + bid] = h[b];
}

// ---------- single-pass chunk scan: arr -> per-chunk exclusive, bsum = chunk sums ----------
__global__ __launch_bounds__(256) void scan_partial_kernel(int* __restrict__ arr, int Ntot,
                                                           int* __restrict__ bsum) {
    __shared__ int ws[256];
    const int t = threadIdx.x;
    const int i0 = blockIdx.x * SCAN_CHUNK + t * 4;
    int4 v = {0, 0, 0, 0};
    if (i0 + 3 < Ntot) {
        v = *reinterpret_cast<const int4*>(arr + i0);
    } else {
        if (i0 < Ntot) v.x = arr[i0];
        if (i0 + 1 < Ntot) v.y = arr[i0 + 1];
        if (i0 + 2 < Ntot) v.z = arr[i0 + 2];
        if (i0 + 3 < Ntot) v.w = arr[i0 + 3];
    }
    ws[t] = v.x + v.y + v.z + v.w;
    __syncthreads();
    for (int off = 1; off < 256; off <<= 1) {
        int val = (t >= off) ? ws[t - off] : 0;
        __syncthreads();
        ws[t] += val;
        __syncthreads();
    }
    int ex = t ? ws[t - 1] : 0;
    int e0 = ex, e1 = ex + v.x, e2 = e1 + v.y, e3 = e2 + v.z;
    if (i0 + 3 < Ntot) {
        *reinterpret_cast<int4*>(arr + i0) = make_int4(e0, e1, e2, e3);
    } else {
        if (i0 < Ntot) arr[i0] = e0;
        if (i0 + 1 < Ntot) arr[i0 + 1] = e1;
        if (i0 + 2 < Ntot) arr[i0 + 2] = e2;
        if (i0 + 3 < Ntot) arr[i0 + 3] = e3;
    }
    if (t == 255) bsum[blockIdx.x] = ws[255];
}

// ---------- in-block inclusive scan of bsum[0..nb2) into sb[256] (nb2 <= 256) ----------
__device__ __forceinline__ void scan_bsum_lds(const int* __restrict__ bsum, int nb2,
                                              int* sb) {
    const int t = threadIdx.x;
    sb[t] = (t < nb2) ? bsum[t] : 0;
    __syncthreads();
    for (int off = 1; off < 256; off <<= 1) {
        int v = (t >= off) ? sb[t - off] : 0;
        __syncthreads();
        sb[t] += v;
        __syncthreads();
    }
    // sb[j] = inclusive sum; exclusive prefix of chunk j = (j ? sb[j-1] : 0)
}

// ---------- partition pass 2: scatter edges grouped by bucket ----------
// ebuf entry packed: src (24 bits) | local_dst (8 bits) << 24.
__global__ __launch_bounds__(256) void part_scatter_kernel(const void* __restrict__ ei, int E,
                                                           int NB, int NBLK, int SH,
                                                           const int* __restrict__ histT,
                                                           const int* __restrict__ bsum,
                                                           int nb2,
                                                           unsigned* __restrict__ ebuf) {
    __shared__ int cur[512];
    __shared__ int sb[256];
    const int t = threadIdx.x;
    bool is64 = ei_is64((const int*)ei);
    scan_bsum_lds(bsum, nb2, sb);
    for (int b = t; b < NB; b += 256) {
        int idx = b * NBLK + blockIdx.x;
        int c = idx >> 10;
        cur[b] = histT[idx] + (c ? sb[c - 1] : 0);
    }
    __syncthreads();
    const int base = blockIdx.x * TE;
    for (int i = t; i < TE; i += 256) {
        int e = base + i;
        if (e < E) {
            int s = get_idx(ei, is64, e);
            int d = get_idx(ei, is64, (long long)E + e);
            int pos = atomicAdd(&cur[d >> SH], 1);
            ebuf[pos] = (unsigned)s | ((unsigned)(d & ((1 << SH) - 1)) << 24);
        }
    }
}

// ---------- per-bucket CSR: LDS node-histogram + scan, contiguous col writes ----------
__global__ __launch_bounds__(256) void bucket_csr_kernel(const unsigned* __restrict__ ebuf,
                                                         const int* __restrict__ histT,
                                                         const int* __restrict__ bsum,
                                                         int nb2,
                                                         int NB, int NBLK, int SH, int E,
                                                         int N, int* __restrict__ rs,
                                                         int* __restrict__ col) {
    const int b = blockIdx.x, t = threadIdx.x;
    const int nodes = 1 << SH;  // 256
    __shared__ int h[256];
    __shared__ int cur[256];
    __shared__ int sb[256];
    __shared__ int sse[2];
    scan_bsum_lds(bsum, nb2, sb);
    if (t == 0) {
        int i0 = b * NBLK;
        int c0 = i0 >> 10;
        sse[0] = histT[i0] + (c0 ? sb[c0 - 1] : 0);
        if (b + 1 < NB) {
            int i1 = (b + 1) * NBLK;
            int c1 = i1 >> 10;
            sse[1] = histT[i1] + (c1 ? sb[c1 - 1] : 0);
        } else {
            sse[1] = E;
        }
    }
    h[t] = 0;
    __syncthreads();
    const int bstart = sse[0], bend = sse[1];
    for (int i = bstart + t; i < bend; i += 256) {
        atomicAdd(&h[ebuf[i] >> 24], 1);
    }
    __syncthreads();
    for (int off = 1; off < nodes; off <<= 1) {
        int v = (t >= off) ? h[t - off] : 0;
        __syncthreads();
        h[t] += v;
        __syncthreads();
    }
    const int node0 = b << SH;
    {
        int node = node0 + t;
        if (node < N) rs[node] = bstart + h[t];      // end offset
        cur[t] = bstart + (t ? h[t - 1] : 0);        // start offset
    }
    __syncthreads();
    for (int i = bstart + t; i < bend; i += 256) {
        unsigned ed = ebuf[i];
        int pos = atomicAdd(&cur[ed >> 24], 1);
        col[pos] = (int)(ed & 0xFFFFFFu);
    }
}

// ---------- gather-aggregate (mean), fp8 in / bf16 out ----------
// One quarter-wave owns TWO independent node streams (vA = base+Q, vB = vA+16):
// the common loop issues both streams' 8-wide batches back-to-back -> 16
// gathers in flight per lane; tails are masked batches, mutually independent.
__device__ __forceinline__ void acc8(f32x2& a0, f32x2& a1, f32x2& a2, f32x2& a3,
                                     uint2 d) {
    a0 += __builtin_amdgcn_cvt_pk_f32_fp8((int)d.x, false);
    a1 += __builtin_amdgcn_cvt_pk_f32_fp8((int)d.x, true);
    a2 += __builtin_amdgcn_cvt_pk_f32_fp8((int)d.y, false);
    a3 += __builtin_amdgcn_cvt_pk_f32_fp8((int)d.y, true);
}

__device__ __forceinline__ void gather_batch8(
    const unsigned char* __restrict__ xq, const int* __restrict__ col, int e,
    unsigned lcoff, f32x2& a0, f32x2& a1, f32x2& a2, f32x2& a3) {
    int c0 = col[e], c1 = col[e + 1], c2 = col[e + 2], c3 = col[e + 3];
    int c4 = col[e + 4], c5 = col[e + 5], c6 = col[e + 6], c7 = col[e + 7];
    uint2 d0 = *reinterpret_cast<const uint2*>(xq + (((unsigned)c0) << 7) + lcoff);
    uint2 d1 = *reinterpret_cast<const uint2*>(xq + (((unsigned)c1) << 7) + lcoff);
    uint2 d2 = *reinterpret_cast<const uint2*>(xq + (((unsigned)c2) << 7) + lcoff);
    uint2 d3 = *reinterpret_cast<const uint2*>(xq + (((unsigned)c3) << 7) + lcoff);
    uint2 d4 = *reinterpret_cast<const uint2*>(xq + (((unsigned)c4) << 7) + lcoff);
    uint2 d5 = *reinterpret_cast<const uint2*>(xq + (((unsigned)c5) << 7) + lcoff);
    uint2 d6 = *reinterpret_cast<const uint2*>(xq + (((unsigned)c6) << 7) + lcoff);
    uint2 d7 = *reinterpret_cast<const uint2*>(xq + (((unsigned)c7) << 7) + lcoff);
    acc8(a0, a1, a2, a3, d0); acc8(a0, a1, a2, a3, d1);
    acc8(a0, a1, a2, a3, d2); acc8(a0, a1, a2, a3, d3);
    acc8(a0, a1, a2, a3, d4); acc8(a0, a1, a2, a3, d5);
    acc8(a0, a1, a2, a3, d6); acc8(a0, a1, a2, a3, d7);
}

__device__ __forceinline__ void gather_masked(
    const unsigned char* __restrict__ xq, const int* __restrict__ col, int e, int end,
    unsigned lcoff, f32x2& a0, f32x2& a1, f32x2& a2, f32x2& a3) {
    const int l = end - 1;
    int i1 = e + 1 < end ? e + 1 : l;
    int i2 = e + 2 < end ? e + 2 : l;
    int i3 = e + 3 < end ? e + 3 : l;
    int i4 = e + 4 < end ? e + 4 : l;
    int i5 = e + 5 < end ? e + 5 : l;
    int i6 = e + 6 < end ? e + 6 : l;
    int c0 = col[e], c1 = col[i1], c2 = col[i2], c3 = col[i3];
    int c4 = col[i4], c5 = col[i5], c6 = col[i6];
    uint2 d0 = *reinterpret_cast<const uint2*>(xq + (((unsigned)c0) << 7) + lcoff);
    uint2 d1 = *reinterpret_cast<const uint2*>(xq + (((unsigned)c1) << 7) + lcoff);
    uint2 d2 = *reinterpret_cast<const uint2*>(xq + (((unsigned)c2) << 7) + lcoff);
    uint2 d3 = *reinterpret_cast<const uint2*>(xq + (((unsigned)c3) << 7) + lcoff);
    uint2 d4 = *reinterpret_cast<const uint2*>(xq + (((unsigned)c4) << 7) + lcoff);
    uint2 d5 = *reinterpret_cast<const uint2*>(xq + (((unsigned)c5) << 7) + lcoff);
    uint2 d6 = *reinterpret_cast<const uint2*>(xq + (((unsigned)c6) << 7) + lcoff);
    d1.x = (e + 1 < end) ? d1.x : 0u; d1.y = (e + 1 < end) ? d1.y : 0u;
    d2.x = (e + 2 < end) ? d2.x : 0u; d2.y = (e + 2 < end) ? d2.y : 0u;
    d3.x = (e + 3 < end) ? d3.x : 0u; d3.y = (e + 3 < end) ? d3.y : 0u;
    d4.x = (e + 4 < end) ? d4.x : 0u; d4.y = (e + 4 < end) ? d4.y : 0u;
    d5.x = (e + 5 < end) ? d5.x : 0u; d5.y = (e + 5 < end) ? d5.y : 0u;
    d6.x = (e + 6 < end) ? d6.x : 0u; d6.y = (e + 6 < end) ? d6.y : 0u;
    acc8(a0, a1, a2, a3, d0); acc8(a0, a1, a2, a3, d1);
    acc8(a0, a1, a2, a3, d2); acc8(a0, a1, a2, a3, d3);
    acc8(a0, a1, a2, a3, d4); acc8(a0, a1, a2, a3, d5);
    acc8(a0, a1, a2, a3, d6);
}

__device__ __forceinline__ void store_mean(ushort* __restrict__ outm, int v, int lc,
                                           int deg, f32x2 a0, f32x2 a1, f32x2 a2,
                                           f32x2 a3) {
    float inv = (deg > 0) ? 1.0f / (float)deg : 0.f;
    __hip_bfloat16 o[8];
    o[0] = __float2bfloat16(a0.x * inv); o[1] = __float2bfloat16(a0.y * inv);
    o[2] = __float2bfloat16(a1.x * inv); o[3] = __float2bfloat16(a1.y * inv);
    o[4] = __float2bfloat16(a2.x * inv); o[5] = __float2bfloat16(a2.y * inv);
    o[6] = __float2bfloat16(a3.x * inv); o[7] = __float2bfloat16(a3.y * inv);
    *reinterpret_cast<uint4*>(outm + (size_t)v * D + (lc << 3)) =
        *reinterpret_cast<uint4*>(o);
}

__global__ __launch_bounds__(256) void aggregate_mean_fp8_kernel(
    const unsigned char* __restrict__ xq, const int* __restrict__ rs,
    const int* __restrict__ col, ushort* __restrict__ outm, int N) {
    const int t = threadIdx.x;
    const int Q = t >> 4;                 // quarter-wave id 0..15
    const int lc = t & 15;
    const unsigned lcoff = (unsigned)lc * 8u;
    const int vA = blockIdx.x * 32 + Q;
    const int vB = vA + 16;

    int sA = 0, nA = 0, sB = 0, nB = 0;
    if (vA < N) { sA = vA ? rs[vA - 1] : 0; nA = rs[vA]; }
    if (vB < N) { sB = rs[vB - 1]; nB = rs[vB]; }

    f32x2 aA0 = {0.f, 0.f}, aA1 = {0.f, 0.f}, aA2 = {0.f, 0.f}, aA3 = {0.f, 0.f};
    f32x2 aB0 = {0.f, 0.f}, aB1 = {0.f, 0.f}, aB2 = {0.f, 0.f}, aB3 = {0.f, 0.f};

    int fA = (nA - sA) >> 3, fB = (nB - sB) >> 3;
    int eA = sA, eB = sB;
    const int common = fA < fB ? fA : fB;
    for (int i = 0; i < common; ++i) {
        gather_batch8(xq, col, eA, lcoff, aA0, aA1, aA2, aA3);
        gather_batch8(xq, col, eB, lcoff, aB0, aB1, aB2, aB3);
        eA += 8; eB += 8;
    }
    for (int i = common; i < fA; ++i) {
        gather_batch8(xq, col, eA, lcoff, aA0, aA1, aA2, aA3);
        eA += 8;
    }
    for (int i = common; i < fB; ++i) {
        gather_batch8(xq, col, eB, lcoff, aB0, aB1, aB2, aB3);
        eB += 8;
    }
    if (eA < nA) gather_masked(xq, col, eA, nA, lcoff, aA0, aA1, aA2, aA3);
    if (eB < nB) gather_masked(xq, col, eB, nB, lcoff, aB0, aB1, aB2, aB3);

    if (vA < N) store_mean(outm, vA, lc, nA - sA, aA0, aA1, aA2, aA3);
    if (vB < N) store_mean(outm, vB, lc, nB - sB, aB0, aB1, aB2, aB3);
}

// ---------- MFMA GEMM, LDS-staged frag-major B ----------
template <typename OutT, bool DUAL, bool SELFF32>
__global__ __launch_bounds__(512) void sage_mfma_kernel(
    const ushort* __restrict__ Ab, const void* __restrict__ Sb,
    const ushort* __restrict__ Wf, const float* __restrict__ bias,
    OutT* __restrict__ out, unsigned char* __restrict__ fq, int N) {
    __shared__ uint4 ldsB[4096];  // 64 KB
    const int t = threadIdx.x;
    {
        const uint4* g = reinterpret_cast<const uint4*>(Wf);
#pragma unroll
        for (int i = 0; i < 8; ++i) ldsB[t + i * 512] = g[t + i * 512];
    }
    __syncthreads();

    const int lane = t & 63, w = t >> 6;
    const int lm = lane & 15;
    const int ksub = (lane >> 4) * 8;
    const int mbase = blockIdx.x * 128 + w * 16;

    int r0 = mbase + lm;
    if (r0 >= N) r0 = N - 1;

    f32x4 acc[8];
#pragma unroll
    for (int j = 0; j < 8; ++j) {
        float bv = bias[j * 16 + lm];
        acc[j] = {bv, bv, bv, bv};
    }

    const ushort* A0 = Ab + (size_t)r0 * D + ksub;
    const ushort* lB = reinterpret_cast<const ushort*>(ldsB) + lane * 8;

#pragma unroll
    for (int s = 0; s < 8; ++s) {
        bf16x8 a;
        if (s < 4) {
            a = *reinterpret_cast<const bf16x8*>(A0 + s * 32);
        } else if constexpr (SELFF32) {
            const float* S0 = (const float*)Sb + (size_t)r0 * D + (s - 4) * 32 + ksub;
            float4 v0 = *reinterpret_cast<const float4*>(S0);
            float4 v1 = *reinterpret_cast<const float4*>(S0 + 4);
            __hip_bfloat16 o[8];
            o[0] = __float2bfloat16(v0.x); o[1] = __float2bfloat16(v0.y);
            o[2] = __float2bfloat16(v0.z); o[3] = __float2bfloat16(v0.w);
            o[4] = __float2bfloat16(v1.x); o[5] = __float2bfloat16(v1.y);
            o[6] = __float2bfloat16(v1.z); o[7] = __float2bfloat16(v1.w);
            a = *reinterpret_cast<bf16x8*>(o);
        } else {
            const ushort* S0 = (const ushort*)Sb + (size_t)r0 * D + ksub;
            a = *reinterpret_cast<const bf16x8*>(S0 + (s - 4) * 32);
        }
#pragma unroll
        for (int j = 0; j < 8; ++j) {
            bf16x8 b = *reinterpret_cast<const bf16x8*>(lB + (j * 8 + s) * 512);
            acc[j] = __builtin_amdgcn_mfma_f32_16x16x32_bf16(a, b, acc[j], 0, 0, 0);
        }
    }

    const int rr = (lane >> 4) * 4;
#pragma unroll
    for (int r = 0; r < 4; ++r) {
        int row = mbase + rr + r;
        if (row < N) {
#pragma unroll
            for (int j = 0; j < 8; ++j) {
                float val = acc[j][r];
                if constexpr (sizeof(OutT) == 2)
                    out[(size_t)row * D + j * 16 + lm] = __float2bfloat16(val);
                else
                    out[(size_t)row * D + j * 16 + lm] = val;
                if constexpr (DUAL) {
                    int pk = __builtin_amdgcn_cvt_pk_fp8_f32(val, val, 0, false);
                    fq[(size_t)row * D + j * 16 + lm] = (unsigned char)(pk & 0xff);
                }
            }
        }
    }
}

extern "C" void kernel_launch(void* const* d_in, const int* in_sizes, int n_in,
                              void* d_out, int out_size, void* d_ws, size_t ws_size,
                              hipStream_t stream) {
    const float* x   = (const float*)d_in[0];
    const void*  ei  = d_in[1];
    const float* Wl1 = (const float*)d_in[2];
    const float* Wr1 = (const float*)d_in[3];
    const float* b1  = (const float*)d_in[4];
    const float* Wl2 = (const float*)d_in[5];
    const float* Wr2 = (const float*)d_in[6];
    const float* b2  = (const float*)d_in[7];
    float* out = (float*)d_out;

    const int N = in_sizes[0] / D;
    const int E = in_sizes[1] / 2;
    const long long ND = (long long)N * D;

    // bucket shift: keep NB <= 512 (N=100000 -> SH=8, NB=391)
    int SH = 8;
    while (((N + (1 << SH) - 1) >> SH) > 512) ++SH;
    const int NB = (N + (1 << SH) - 1) >> SH;
    const int NBLK = (E + TE - 1) / TE;
    const int Ntot = NB * NBLK;
    const int nb2 = (Ntot + SCAN_CHUNK - 1) / SCAN_CHUNK;  // must be <= 256

    // ws layout (bf16 = ushort)
    ushort* meanb = (ushort*)d_ws;                      // N*D
    ushort* h1b   = meanb + ND;                         // N*D
    ushort* Wf1   = h1b + ND;                           // 4096*8
    ushort* Wf2   = Wf1 + 32768;                        // 4096*8
    int*    rs    = (int*)(Wf2 + 32768);                // N
    int*    col   = rs + N;                             // E
    // transient aliases (dead before their hosts are written):
    int*      histT = (int*)meanb;                      // NB*NBLK (meanb written later)
    int*      bsum  = histT + Ntot;                     // nb2
    unsigned* ebuf  = (unsigned*)h1b;                   // E packed (h1b written later)
    // d_out carve-up (both dead before GEMM2 writes out):
    //   [0, ND): xq fp8; [ND, 2*ND): h1q fp8
    unsigned char* xq  = (unsigned char*)d_out;
    unsigned char* h1q = (unsigned char*)d_out + ND;

    const int ncvt = (int)((ND / 8 + 255) / 256);

    // ---- prep: fp8 convert + frag-major weights + partition histogram ----
    prep_kernel<<<ncvt + 32 + NBLK, 256, 0, stream>>>(
        x, (unsigned*)xq, ND, ncvt, Wl1, Wr1, Wl2, Wr2,
        Wf1, Wf2, ei, E, NB, NBLK, SH, histT);

    // ---- CSR via two-level counting sort (LDS atomics only; no scan_top) ----
    scan_partial_kernel<<<nb2, 256, 0, stream>>>(histT, Ntot, bsum);
    part_scatter_kernel<<<NBLK, 256, 0, stream>>>(ei, E, NB, NBLK, SH, histT, bsum, nb2, ebuf);
    bucket_csr_kernel<<<NB, 256, 0, stream>>>(ebuf, histT, bsum, nb2, NB, NBLK, SH, E, N, rs, col);

    const int agg_grid = (N + 31) / 32;
    const int gemm_grid = (N + 127) / 128;

    // ---- layer 1: gather fp8 x -> mean; GEMM (self f32 exact) -> h1b + h1q ----
    aggregate_mean_fp8_kernel<<<agg_grid, 256, 0, stream>>>(xq, rs, col, meanb, N);
    sage_mfma_kernel<__hip_bfloat16, true, true><<<gemm_grid, 512, 0, stream>>>(
        meanb, x, Wf1, b1, (__hip_bfloat16*)h1b, h1q, N);

    // ---- layer 2: gather fp8 h1 -> mean; GEMM (self bf16) -> out f32 ----
    aggregate_mean_fp8_kernel<<<agg_grid, 256, 0, stream>>>(h1q, rs, col, meanb, N);
    sage_mfma_kernel<float, false, false><<<gemm_grid, 512, 0, stream>>>(
        meanb, h1b, Wf2, b2, out, nullptr, N);
}

// Round 14
// 160.803 us; speedup vs baseline: 1.0932x; 1.0932x over previous
//
#include <hip/hip_runtime.h>
#include <hip/hip_bf16.h>

#define D 128
#define SCAN_CHUNK 1024
#define TE 4096  // edges per partition block

typedef __attribute__((ext_vector_type(8))) short bf16x8;
typedef __attribute__((ext_vector_type(4))) float f32x4;
typedef __attribute__((ext_vector_type(2))) float f32x2;

// ---------- edge-index dtype detection (int64 vs int32, on-device) ----------
__device__ __forceinline__ bool ei_is64(const int* ei32) {
    return (ei32[1] | ei32[3] | ei32[5] | ei32[7]) == 0;
}
__device__ __forceinline__ int get_idx(const void* ei, bool is64, long long pos) {
    return is64 ? (int)((const long long*)ei)[pos] : ((const int*)ei)[pos];
}

// ---------- prep: x->fp8 | frag-major weight build | partition histogram ----------
__global__ __launch_bounds__(256) void prep_kernel(
    const float* __restrict__ x, unsigned* __restrict__ xq, long long ND, int ncvt,
    const float* __restrict__ Wl1, const float* __restrict__ Wr1,
    const float* __restrict__ Wl2, const float* __restrict__ Wr2,
    ushort* __restrict__ Wf1, ushort* __restrict__ Wf2,
    const void* __restrict__ ei, int E, int NB, int NBLK, int SH,
    int* __restrict__ histT) {
    __shared__ int h[512];
    const int t = threadIdx.x;
    int bid = blockIdx.x;

    if (bid < ncvt) {
        long long i = ((long long)bid * 256 + t) * 8;
        if (i + 7 < ND) {
            float4 v0 = *reinterpret_cast<const float4*>(x + i);
            float4 v1 = *reinterpret_cast<const float4*>(x + i + 4);
            int p0 = __builtin_amdgcn_cvt_pk_fp8_f32(v0.x, v0.y, 0, false);
            p0 = __builtin_amdgcn_cvt_pk_fp8_f32(v0.z, v0.w, p0, true);
            int p1 = __builtin_amdgcn_cvt_pk_fp8_f32(v1.x, v1.y, 0, false);
            p1 = __builtin_amdgcn_cvt_pk_fp8_f32(v1.z, v1.w, p1, true);
            *reinterpret_cast<uint2*>(reinterpret_cast<unsigned char*>(xq) + i) =
                make_uint2((unsigned)p0, (unsigned)p1);
        } else {
            for (; i < ND; ++i) {
                int pk = __builtin_amdgcn_cvt_pk_fp8_f32(x[i], x[i], 0, false);
                reinterpret_cast<unsigned char*>(xq)[i] = (unsigned char)(pk & 0xff);
            }
        }
        return;
    }
    bid -= ncvt;
    if (bid < 32) {
        int gid = bid * 256 + t;           // 8192 threads: 2 layers x 4096 slots
        int id = gid & 4095;
        const float* Wl = Wl1; const float* Wr = Wr1; ushort* Wf = Wf1;
        if (gid >= 4096) { Wl = Wl2; Wr = Wr2; Wf = Wf2; }
        int lane = id & 63, s = (id >> 6) & 7, j = id >> 9;
        int c = j * 16 + (lane & 15);
        int k = s * 32 + ((lane >> 4) << 3);  // 8 consecutive k from here
        const float* src = (k < 128) ? (Wl + c * 128 + k) : (Wr + c * 128 + (k - 128));
        float4 v0 = *reinterpret_cast<const float4*>(src);
        float4 v1 = *reinterpret_cast<const float4*>(src + 4);
        __hip_bfloat16 o[8];
        o[0] = __float2bfloat16(v0.x); o[1] = __float2bfloat16(v0.y);
        o[2] = __float2bfloat16(v0.z); o[3] = __float2bfloat16(v0.w);
        o[4] = __float2bfloat16(v1.x); o[5] = __float2bfloat16(v1.y);
        o[6] = __float2bfloat16(v1.z); o[7] = __float2bfloat16(v1.w);
        *reinterpret_cast<uint4*>(Wf + (size_t)id * 8) = *reinterpret_cast<uint4*>(o);
        return;
    }
    bid -= 32;
    // partition histogram over buckets for edge tile bid
    for (int b = t; b < 512; b += 256) h[b] = 0;
    bool is64 = ei_is64((const int*)ei);
    __syncthreads();
    const int base = bid * TE;
    for (int i = t; i < TE; i += 256) {
        int e = base + i;
        if (e < E) {
            int d = get_idx(ei, is64, (long long)E + e);
            atomicAdd(&h[d >> SH], 1);
        }
    }
    __syncthreads();
    for (int b = t; b < NB; b += 256) histT[b * NBLK + bid] = h[b];
}

// ---------- single-pass chunk scan: arr -> per-chunk exclusive, bsum = chunk sums ----------
__global__ __launch_bounds__(256) void scan_partial_kernel(int* __restrict__ arr, int Ntot,
                                                           int* __restrict__ bsum) {
    __shared__ int ws[256];
    const int t = threadIdx.x;
    const int i0 = blockIdx.x * SCAN_CHUNK + t * 4;
    int4 v = {0, 0, 0, 0};
    if (i0 + 3 < Ntot) {
        v = *reinterpret_cast<const int4*>(arr + i0);
    } else {
        if (i0 < Ntot) v.x = arr[i0];
        if (i0 + 1 < Ntot) v.y = arr[i0 + 1];
        if (i0 + 2 < Ntot) v.z = arr[i0 + 2];
        if (i0 + 3 < Ntot) v.w = arr[i0 + 3];
    }
    ws[t] = v.x + v.y + v.z + v.w;
    __syncthreads();
    for (int off = 1; off < 256; off <<= 1) {
        int val = (t >= off) ? ws[t - off] : 0;
        __syncthreads();
        ws[t] += val;
        __syncthreads();
    }
    int ex = t ? ws[t - 1] : 0;
    int e0 = ex, e1 = ex + v.x, e2 = e1 + v.y, e3 = e2 + v.z;
    if (i0 + 3 < Ntot) {
        *reinterpret_cast<int4*>(arr + i0) = make_int4(e0, e1, e2, e3);
    } else {
        if (i0 < Ntot) arr[i0] = e0;
        if (i0 + 1 < Ntot) arr[i0 + 1] = e1;
        if (i0 + 2 < Ntot) arr[i0 + 2] = e2;
        if (i0 + 3 < Ntot) arr[i0 + 3] = e3;
    }
    if (t == 255) bsum[blockIdx.x] = ws[255];
}

// ---------- in-block inclusive scan of bsum[0..nb2) into sb[256] (nb2 <= 256) ----------
__device__ __forceinline__ void scan_bsum_lds(const int* __restrict__ bsum, int nb2,
                                              int* sb) {
    const int t = threadIdx.x;
    sb[t] = (t < nb2) ? bsum[t] : 0;
    __syncthreads();
    for (int off = 1; off < 256; off <<= 1) {
        int v = (t >= off) ? sb[t - off] : 0;
        __syncthreads();
        sb[t] += v;
        __syncthreads();
    }
    // sb[j] = inclusive sum; exclusive prefix of chunk j = (j ? sb[j-1] : 0)
}

// ---------- partition pass 2: scatter edges grouped by bucket ----------
// ebuf entry packed: src (24 bits) | local_dst (8 bits) << 24.
__global__ __launch_bounds__(256) void part_scatter_kernel(const void* __restrict__ ei, int E,
                                                           int NB, int NBLK, int SH,
                                                           const int* __restrict__ histT,
                                                           const int* __restrict__ bsum,
                                                           int nb2,
                                                           unsigned* __restrict__ ebuf) {
    __shared__ int cur[512];
    __shared__ int sb[256];
    const int t = threadIdx.x;
    bool is64 = ei_is64((const int*)ei);
    scan_bsum_lds(bsum, nb2, sb);
    for (int b = t; b < NB; b += 256) {
        int idx = b * NBLK + blockIdx.x;
        int c = idx >> 10;
        cur[b] = histT[idx] + (c ? sb[c - 1] : 0);
    }
    __syncthreads();
    const int base = blockIdx.x * TE;
    for (int i = t; i < TE; i += 256) {
        int e = base + i;
        if (e < E) {
            int s = get_idx(ei, is64, e);
            int d = get_idx(ei, is64, (long long)E + e);
            int pos = atomicAdd(&cur[d >> SH], 1);
            ebuf[pos] = (unsigned)s | ((unsigned)(d & ((1 << SH) - 1)) << 24);
        }
    }
}

// ---------- per-bucket CSR: LDS node-histogram + scan, contiguous col writes ----------
__global__ __launch_bounds__(256) void bucket_csr_kernel(const unsigned* __restrict__ ebuf,
                                                         const int* __restrict__ histT,
                                                         const int* __restrict__ bsum,
                                                         int nb2,
                                                         int NB, int NBLK, int SH, int E,
                                                         int N, int* __restrict__ rs,
                                                         int* __restrict__ col) {
    const int b = blockIdx.x, t = threadIdx.x;
    const int nodes = 1 << SH;  // 256
    __shared__ int h[256];
    __shared__ int cur[256];
    __shared__ int sb[256];
    __shared__ int sse[2];
    scan_bsum_lds(bsum, nb2, sb);
    if (t == 0) {
        int i0 = b * NBLK;
        int c0 = i0 >> 10;
        sse[0] = histT[i0] + (c0 ? sb[c0 - 1] : 0);
        if (b + 1 < NB) {
            int i1 = (b + 1) * NBLK;
            int c1 = i1 >> 10;
            sse[1] = histT[i1] + (c1 ? sb[c1 - 1] : 0);
        } else {
            sse[1] = E;
        }
    }
    h[t] = 0;
    __syncthreads();
    const int bstart = sse[0], bend = sse[1];
    for (int i = bstart + t; i < bend; i += 256) {
        atomicAdd(&h[ebuf[i] >> 24], 1);
    }
    __syncthreads();
    for (int off = 1; off < nodes; off <<= 1) {
        int v = (t >= off) ? h[t - off] : 0;
        __syncthreads();
        h[t] += v;
        __syncthreads();
    }
    const int node0 = b << SH;
    {
        int node = node0 + t;
        if (node < N) rs[node] = bstart + h[t];      // end offset
        cur[t] = bstart + (t ? h[t - 1] : 0);        // start offset
    }
    __syncthreads();
    for (int i = bstart + t; i < bend; i += 256) {
        unsigned ed = ebuf[i];
        int pos = atomicAdd(&cur[ed >> 24], 1);
        col[pos] = (int)(ed & 0xFFFFFFu);
    }
}

// ---------- gather-aggregate (mean), fp8 in / bf16 out ----------
// One QUARTER-WAVE (16 lanes x 8B = full 128B row) owns one node.
// 8-wide main batch (8 col + 8 gathers in flight) -> 4-wide -> one MASKED
// final batch (clamped index, raw bytes zeroed via cndmask; fp8 0x00 -> 0.0).
__device__ __forceinline__ void acc8(f32x2& a0, f32x2& a1, f32x2& a2, f32x2& a3,
                                     uint2 d) {
    a0 += __builtin_amdgcn_cvt_pk_f32_fp8((int)d.x, false);
    a1 += __builtin_amdgcn_cvt_pk_f32_fp8((int)d.x, true);
    a2 += __builtin_amdgcn_cvt_pk_f32_fp8((int)d.y, false);
    a3 += __builtin_amdgcn_cvt_pk_f32_fp8((int)d.y, true);
}

__global__ __launch_bounds__(256) void aggregate_mean_fp8_kernel(
    const unsigned char* __restrict__ xq, const int* __restrict__ rs,
    const int* __restrict__ col, ushort* __restrict__ outm, int N) {
    const int t = threadIdx.x;
    const int v = blockIdx.x * 16 + (t >> 4);
    if (v >= N) return;
    const unsigned lcoff = (unsigned)(t & 15) * 8u;
    const int start = v ? rs[v - 1] : 0, end = rs[v];
    f32x2 a0 = {0.f, 0.f}, a1 = {0.f, 0.f}, a2 = {0.f, 0.f}, a3 = {0.f, 0.f};
    int e = start;
    // ---- 8-wide main batches ----
    for (; e + 7 < end; e += 8) {
        int c0 = col[e], c1 = col[e + 1], c2 = col[e + 2], c3 = col[e + 3];
        int c4 = col[e + 4], c5 = col[e + 5], c6 = col[e + 6], c7 = col[e + 7];
        uint2 d0 = *reinterpret_cast<const uint2*>(xq + (((unsigned)c0) << 7) + lcoff);
        uint2 d1 = *reinterpret_cast<const uint2*>(xq + (((unsigned)c1) << 7) + lcoff);
        uint2 d2 = *reinterpret_cast<const uint2*>(xq + (((unsigned)c2) << 7) + lcoff);
        uint2 d3 = *reinterpret_cast<const uint2*>(xq + (((unsigned)c3) << 7) + lcoff);
        uint2 d4 = *reinterpret_cast<const uint2*>(xq + (((unsigned)c4) << 7) + lcoff);
        uint2 d5 = *reinterpret_cast<const uint2*>(xq + (((unsigned)c5) << 7) + lcoff);
        uint2 d6 = *reinterpret_cast<const uint2*>(xq + (((unsigned)c6) << 7) + lcoff);
        uint2 d7 = *reinterpret_cast<const uint2*>(xq + (((unsigned)c7) << 7) + lcoff);
        acc8(a0, a1, a2, a3, d0); acc8(a0, a1, a2, a3, d1);
        acc8(a0, a1, a2, a3, d2); acc8(a0, a1, a2, a3, d3);
        acc8(a0, a1, a2, a3, d4); acc8(a0, a1, a2, a3, d5);
        acc8(a0, a1, a2, a3, d6); acc8(a0, a1, a2, a3, d7);
    }
    // ---- 4-wide ----
    for (; e + 3 < end; e += 4) {
        int c0 = col[e], c1 = col[e + 1], c2 = col[e + 2], c3 = col[e + 3];
        uint2 d0 = *reinterpret_cast<const uint2*>(xq + (((unsigned)c0) << 7) + lcoff);
        uint2 d1 = *reinterpret_cast<const uint2*>(xq + (((unsigned)c1) << 7) + lcoff);
        uint2 d2 = *reinterpret_cast<const uint2*>(xq + (((unsigned)c2) << 7) + lcoff);
        uint2 d3 = *reinterpret_cast<const uint2*>(xq + (((unsigned)c3) << 7) + lcoff);
        acc8(a0, a1, a2, a3, d0); acc8(a0, a1, a2, a3, d1);
        acc8(a0, a1, a2, a3, d2); acc8(a0, a1, a2, a3, d3);
    }
    // ---- masked final batch (0..3 edges, fully pipelined) ----
    if (e < end) {
        const int l = end - 1;
        int i1 = e + 1 < end ? e + 1 : l;
        int i2 = e + 2 < end ? e + 2 : l;
        int c0 = col[e], c1 = col[i1], c2 = col[i2];
        uint2 d0 = *reinterpret_cast<const uint2*>(xq + (((unsigned)c0) << 7) + lcoff);
        uint2 d1 = *reinterpret_cast<const uint2*>(xq + (((unsigned)c1) << 7) + lcoff);
        uint2 d2 = *reinterpret_cast<const uint2*>(xq + (((unsigned)c2) << 7) + lcoff);
        d1.x = (e + 1 < end) ? d1.x : 0u; d1.y = (e + 1 < end) ? d1.y : 0u;
        d2.x = (e + 2 < end) ? d2.x : 0u; d2.y = (e + 2 < end) ? d2.y : 0u;
        acc8(a0, a1, a2, a3, d0); acc8(a0, a1, a2, a3, d1);
        acc8(a0, a1, a2, a3, d2);
    }
    float inv = (end > start) ? 1.0f / (float)(end - start) : 0.f;
    __hip_bfloat16 o[8];
    o[0] = __float2bfloat16(a0.x * inv); o[1] = __float2bfloat16(a0.y * inv);
    o[2] = __float2bfloat16(a1.x * inv); o[3] = __float2bfloat16(a1.y * inv);
    o[4] = __float2bfloat16(a2.x * inv); o[5] = __float2bfloat16(a2.y * inv);
    o[6] = __float2bfloat16(a3.x * inv); o[7] = __float2bfloat16(a3.y * inv);
    *reinterpret_cast<uint4*>(outm + (size_t)v * D + ((t & 15) << 3)) =
        *reinterpret_cast<uint4*>(o);
}

// ---------- MFMA GEMM, LDS-staged frag-major B ----------
template <typename OutT, bool DUAL, bool SELFF32>
__global__ __launch_bounds__(512) void sage_mfma_kernel(
    const ushort* __restrict__ Ab, const void* __restrict__ Sb,
    const ushort* __restrict__ Wf, const float* __restrict__ bias,
    OutT* __restrict__ out, unsigned char* __restrict__ fq, int N) {
    __shared__ uint4 ldsB[4096];  // 64 KB
    const int t = threadIdx.x;
    {
        const uint4* g = reinterpret_cast<const uint4*>(Wf);
#pragma unroll
        for (int i = 0; i < 8; ++i) ldsB[t + i * 512] = g[t + i * 512];
    }
    __syncthreads();

    const int lane = t & 63, w = t >> 6;
    const int lm = lane & 15;
    const int ksub = (lane >> 4) * 8;
    const int mbase = blockIdx.x * 128 + w * 16;

    int r0 = mbase + lm;
    if (r0 >= N) r0 = N - 1;

    f32x4 acc[8];
#pragma unroll
    for (int j = 0; j < 8; ++j) {
        float bv = bias[j * 16 + lm];
        acc[j] = {bv, bv, bv, bv};
    }

    const ushort* A0 = Ab + (size_t)r0 * D + ksub;
    const ushort* lB = reinterpret_cast<const ushort*>(ldsB) + lane * 8;

#pragma unroll
    for (int s = 0; s < 8; ++s) {
        bf16x8 a;
        if (s < 4) {
            a = *reinterpret_cast<const bf16x8*>(A0 + s * 32);
        } else if constexpr (SELFF32) {
            const float* S0 = (const float*)Sb + (size_t)r0 * D + (s - 4) * 32 + ksub;
            float4 v0 = *reinterpret_cast<const float4*>(S0);
            float4 v1 = *reinterpret_cast<const float4*>(S0 + 4);
            __hip_bfloat16 o[8];
            o[0] = __float2bfloat16(v0.x); o[1] = __float2bfloat16(v0.y);
            o[2] = __float2bfloat16(v0.z); o[3] = __float2bfloat16(v0.w);
            o[4] = __float2bfloat16(v1.x); o[5] = __float2bfloat16(v1.y);
            o[6] = __float2bfloat16(v1.z); o[7] = __float2bfloat16(v1.w);
            a = *reinterpret_cast<bf16x8*>(o);
        } else {
            const ushort* S0 = (const ushort*)Sb + (size_t)r0 * D + ksub;
            a = *reinterpret_cast<const bf16x8*>(S0 + (s - 4) * 32);
        }
#pragma unroll
        for (int j = 0; j < 8; ++j) {
            bf16x8 b = *reinterpret_cast<const bf16x8*>(lB + (j * 8 + s) * 512);
            acc[j] = __builtin_amdgcn_mfma_f32_16x16x32_bf16(a, b, acc[j], 0, 0, 0);
        }
    }

    const int rr = (lane >> 4) * 4;
#pragma unroll
    for (int r = 0; r < 4; ++r) {
        int row = mbase + rr + r;
        if (row < N) {
#pragma unroll
            for (int j = 0; j < 8; ++j) {
                float val = acc[j][r];
                if constexpr (sizeof(OutT) == 2)
                    out[(size_t)row * D + j * 16 + lm] = __float2bfloat16(val);
                else
                    out[(size_t)row * D + j * 16 + lm] = val;
                if constexpr (DUAL) {
                    int pk = __builtin_amdgcn_cvt_pk_fp8_f32(val, val, 0, false);
                    fq[(size_t)row * D + j * 16 + lm] = (unsigned char)(pk & 0xff);
                }
            }
        }
    }
}

extern "C" void kernel_launch(void* const* d_in, const int* in_sizes, int n_in,
                              void* d_out, int out_size, void* d_ws, size_t ws_size,
                              hipStream_t stream) {
    const float* x   = (const float*)d_in[0];
    const void*  ei  = d_in[1];
    const float* Wl1 = (const float*)d_in[2];
    const float* Wr1 = (const float*)d_in[3];
    const float* b1  = (const float*)d_in[4];
    const float* Wl2 = (const float*)d_in[5];
    const float* Wr2 = (const float*)d_in[6];
    const float* b2  = (const float*)d_in[7];
    float* out = (float*)d_out;

    const int N = in_sizes[0] / D;
    const int E = in_sizes[1] / 2;
    const long long ND = (long long)N * D;

    // bucket shift: keep NB <= 512 (N=100000 -> SH=8, NB=391)
    int SH = 8;
    while (((N + (1 << SH) - 1) >> SH) > 512) ++SH;
    const int NB = (N + (1 << SH) - 1) >> SH;
    const int NBLK = (E + TE - 1) / TE;
    const int Ntot = NB * NBLK;
    const int nb2 = (Ntot + SCAN_CHUNK - 1) / SCAN_CHUNK;  // must be <= 256

    // ws layout (bf16 = ushort)
    ushort* meanb = (ushort*)d_ws;                      // N*D
    ushort* h1b   = meanb + ND;                         // N*D
    ushort* Wf1   = h1b + ND;                           // 4096*8
    ushort* Wf2   = Wf1 + 32768;                        // 4096*8
    int*    rs    = (int*)(Wf2 + 32768);                // N
    int*    col   = rs + N;                             // E
    // transient aliases (dead before their hosts are written):
    int*      histT = (int*)meanb;                      // NB*NBLK (meanb written later)
    int*      bsum  = histT + Ntot;                     // nb2
    unsigned* ebuf  = (unsigned*)h1b;                   // E packed (h1b written later)
    // d_out carve-up (both dead before GEMM2 writes out):
    //   [0, ND): xq fp8; [ND, 2*ND): h1q fp8
    unsigned char* xq  = (unsigned char*)d_out;
    unsigned char* h1q = (unsigned char*)d_out + ND;

    const int ncvt = (int)((ND / 8 + 255) / 256);

    // ---- prep: fp8 convert + frag-major weights + partition histogram ----
    prep_kernel<<<ncvt + 32 + NBLK, 256, 0, stream>>>(
        x, (unsigned*)xq, ND, ncvt, Wl1, Wr1, Wl2, Wr2,
        Wf1, Wf2, ei, E, NB, NBLK, SH, histT);

    // ---- CSR via two-level counting sort (LDS atomics only; no scan_top) ----
    scan_partial_kernel<<<nb2, 256, 0, stream>>>(histT, Ntot, bsum);
    part_scatter_kernel<<<NBLK, 256, 0, stream>>>(ei, E, NB, NBLK, SH, histT, bsum, nb2, ebuf);
    bucket_csr_kernel<<<NB, 256, 0, stream>>>(ebuf, histT, bsum, nb2, NB, NBLK, SH, E, N, rs, col);

    const int agg_grid = (N + 15) / 16;
    const int gemm_grid = (N + 127) / 128;

    // ---- layer 1: gather fp8 x -> mean; GEMM (self f32 exact) -> h1b + h1q ----
    aggregate_mean_fp8_kernel<<<agg_grid, 256, 0, stream>>>(xq, rs, col, meanb, N);
    sage_mfma_kernel<__hip_bfloat16, true, true><<<gemm_grid, 512, 0, stream>>>(
        meanb, x, Wf1, b1, (__hip_bfloat16*)h1b, h1q, N);

    // ---- layer 2: gather fp8 h1 -> mean; GEMM (self bf16) -> out f32 ----
    aggregate_mean_fp8_kernel<<<agg_grid, 256, 0, stream>>>(h1q, rs, col, meanb, N);
    sage_mfma_kernel<float, false, false><<<gemm_grid, 512, 0, stream>>>(
        meanb, h1b, Wf2, b2, out, nullptr, N);
}